// Round 1
// baseline (264.306 us; speedup 1.0000x reference)
//
#include <hip/hip_runtime.h>
#include <stdint.h>

typedef __attribute__((ext_vector_type(8))) short short8;
typedef __attribute__((ext_vector_type(4))) float f32x4;

#define NB 8
#define RFRM 3
#define HP 32                 // H/PATCH
#define RROWS (RFRM * HP * HP)  // 3072
#define TROWS (HP * HP)         // 1024
#define FEAT 256
#define KCLS 16

static __device__ __forceinline__ unsigned short f2bf(float x) {
  union { float f; uint32_t u; } v; v.f = x;
  uint32_t u = v.u;
  uint32_t r = (u + 0x7fffu + ((u >> 16) & 1u)) >> 16;
  return (unsigned short)r;
}
static __device__ __forceinline__ float bf2f(unsigned short h) {
  union { uint32_t u; float f; } v; v.u = ((uint32_t)h) << 16;
  return v.f;
}

// ---------------- Stage 1: patch-embed conv (fp32 exact), emit bf16 hi/lo ----
// One block = 8 horizontally adjacent patches x 256 out channels.
__global__ __launch_bounds__(256) void feat_kernel(
    const float* __restrict__ ref, const float* __restrict__ tgt,
    const float* __restrict__ wf,
    unsigned short* __restrict__ rh, unsigned short* __restrict__ rl,
    unsigned short* __restrict__ th, unsigned short* __restrict__ tl) {
  __shared__ float strip[192][8];  // [k = ry*24 + kw*3+ci][patch]
  const int tid = threadIdx.x;
  const int gp0 = blockIdx.x * 8;      // first global patch id
  const int b   = gp0 >> 10;           // image 0..31
  const int pi0 = gp0 & 1023;
  const int py  = pi0 >> 5;
  const int px0 = pi0 & 31;            // multiple of 8
  const int n = b >> 2, f = b & 3;
  const float* img = (f < 3) ? (ref + (size_t)(n * 3 + f) * (256 * 256 * 3))
                             : (tgt + (size_t)n * (256 * 256 * 3));
  const float* base = img + (size_t)py * 8 * 768 + (size_t)px0 * 24;
  for (int i = tid; i < 1536; i += 256) {
    int ry = i / 192, col = i - ry * 192;
    float v = base[(size_t)ry * 768 + col];
    strip[ry * 24 + (col % 24)][col / 24] = v;
  }
  __syncthreads();
  float acc[8] = {0.f, 0.f, 0.f, 0.f, 0.f, 0.f, 0.f, 0.f};
#pragma unroll 4
  for (int k = 0; k < 192; ++k) {
    float wv = wf[k * 256 + tid];
    const float4 a  = *(const float4*)&strip[k][0];
    const float4 b4 = *(const float4*)&strip[k][4];
    acc[0] = fmaf(a.x,  wv, acc[0]);
    acc[1] = fmaf(a.y,  wv, acc[1]);
    acc[2] = fmaf(a.z,  wv, acc[2]);
    acc[3] = fmaf(a.w,  wv, acc[3]);
    acc[4] = fmaf(b4.x, wv, acc[4]);
    acc[5] = fmaf(b4.y, wv, acc[5]);
    acc[6] = fmaf(b4.z, wv, acc[6]);
    acc[7] = fmaf(b4.w, wv, acc[7]);
  }
#pragma unroll
  for (int p = 0; p < 8; ++p) {
    const int prow = py * 32 + px0 + p;
    const float v = acc[p];
    const unsigned short h  = f2bf(v);
    const unsigned short lo = f2bf(v - bf2f(h));
    if (f < 3) {
      const size_t row = (size_t)n * RROWS + (size_t)f * 1024 + prow;
      rh[row * 256 + tid] = h;
      rl[row * 256 + tid] = lo;
    } else {
      const size_t row = (size_t)n * TROWS + prow;
      th[row * 256 + tid] = h;
      tl[row * 256 + tid] = lo;
    }
  }
}

// ---------------- Stage 2: fused flash attention (bf16x2 3-pass MFMA) --------
// Grid: 8 n x 32 t-tiles (Tt=32). Block 256 thr = 4 waves. Rt=32 per iter.
__global__ __launch_bounds__(256) void flash_kernel(
    const unsigned short* __restrict__ rh, const unsigned short* __restrict__ rl,
    const unsigned short* __restrict__ th, const unsigned short* __restrict__ tl,
    const float* __restrict__ labels, float* __restrict__ out) {
  __shared__ unsigned short qh[32][264], ql[32][264];
  __shared__ unsigned short kh[32][264], kl[32][264];
  __shared__ float S[32][36];
  __shared__ float2 labt[32][8];

  const int tid = threadIdx.x;
  const int n = blockIdx.x >> 5;
  const int tbase = (blockIdx.x & 31) * 32;

  // stage Q (hi/lo) once
  {
    const int chunk = tid & 31, r0 = tid >> 5;
    const unsigned short* sh = th + ((size_t)n * TROWS + tbase) * 256 + chunk * 8;
    const unsigned short* sl = tl + ((size_t)n * TROWS + tbase) * 256 + chunk * 8;
#pragma unroll
    for (int s = 0; s < 4; ++s) {
      const int r = r0 + s * 8;
      *(short8*)&qh[r][chunk * 8] = *(const short8*)(sh + (size_t)r * 256);
      *(short8*)&ql[r][chunk * 8] = *(const short8*)(sl + (size_t)r * 256);
    }
  }

  const int c = tid >> 3, g = tid & 7;          // phase-B: column, k-group
  const int w = tid >> 6, ri = w >> 1, ti = w & 1;  // MFMA tile ownership
  const int lane = tid & 63, lr = lane & 15, kc = lane >> 4;

  float m = -3.0e38f, lsum = 0.f, a0 = 0.f, a1 = 0.f;

  const unsigned short* khsrc = rh + (size_t)n * RROWS * 256;
  const unsigned short* klsrc = rl + (size_t)n * RROWS * 256;
  const float* labsrc = labels + (size_t)n * RROWS * 16;

  for (int it = 0; it < 96; ++it) {
    const int rbase = it * 32;
    __syncthreads();  // prior PV reads done before restage
    // stage K tile + labels tile
    {
      const int chunk = tid & 31, r0 = tid >> 5;
#pragma unroll
      for (int s = 0; s < 4; ++s) {
        const int r = r0 + s * 8;
        *(short8*)&kh[r][chunk * 8] =
            *(const short8*)(khsrc + (size_t)(rbase + r) * 256 + chunk * 8);
        *(short8*)&kl[r][chunk * 8] =
            *(const short8*)(klsrc + (size_t)(rbase + r) * 256 + chunk * 8);
      }
      labt[tid >> 3][tid & 7] =
          *(const float2*)(labsrc + (size_t)(rbase + (tid >> 3)) * 16 + (tid & 7) * 2);
    }
    __syncthreads();
    // MFMA: S[r][t] = sum_k K[r,k]*Q[t,k], bf16x2 3-pass
    f32x4 acc = {0.f, 0.f, 0.f, 0.f};
#pragma unroll
    for (int ks = 0; ks < 8; ++ks) {
      const int ko = ks * 32 + kc * 8;
      const short8 ah = *(const short8*)&kh[ri * 16 + lr][ko];
      const short8 al = *(const short8*)&kl[ri * 16 + lr][ko];
      const short8 bh = *(const short8*)&qh[ti * 16 + lr][ko];
      const short8 bl = *(const short8*)&ql[ti * 16 + lr][ko];
      acc = __builtin_amdgcn_mfma_f32_16x16x32_bf16(ah, bh, acc, 0, 0, 0);
      acc = __builtin_amdgcn_mfma_f32_16x16x32_bf16(al, bh, acc, 0, 0, 0);
      acc = __builtin_amdgcn_mfma_f32_16x16x32_bf16(ah, bl, acc, 0, 0, 0);
    }
#pragma unroll
    for (int i = 0; i < 4; ++i)
      S[ri * 16 + kc * 4 + i][ti * 16 + lr] = acc[i];
    __syncthreads();
    // online softmax over the 32 new rows (8 lanes per column)
    float s0 = S[g][c], s1 = S[g + 8][c], s2 = S[g + 16][c], s3 = S[g + 24][c];
    float tmax = fmaxf(fmaxf(s0, s1), fmaxf(s2, s3));
    tmax = fmaxf(tmax, __shfl_xor(tmax, 1, 8));
    tmax = fmaxf(tmax, __shfl_xor(tmax, 2, 8));
    tmax = fmaxf(tmax, __shfl_xor(tmax, 4, 8));
    const float mnew = fmaxf(m, tmax);
    const float p0 = __expf(s0 - mnew), p1 = __expf(s1 - mnew);
    const float p2 = __expf(s2 - mnew), p3 = __expf(s3 - mnew);
    float ts = (p0 + p1) + (p2 + p3);
    ts += __shfl_xor(ts, 1, 8);
    ts += __shfl_xor(ts, 2, 8);
    ts += __shfl_xor(ts, 4, 8);
    const float fac = __expf(m - mnew);
    lsum = lsum * fac + ts;
    a0 *= fac; a1 *= fac;
    m = mnew;
    S[g][c] = p0; S[g + 8][c] = p1; S[g + 16][c] = p2; S[g + 24][c] = p3;
    __syncthreads();
    // PV: acc[k] += p[r] * labels[r][k]
#pragma unroll 8
    for (int r = 0; r < 32; ++r) {
      const float wgt = S[r][c];
      const float2 lv = labt[r][g];
      a0 = fmaf(wgt, lv.x, a0);
      a1 = fmaf(wgt, lv.y, a1);
    }
  }
  const float inv = 1.f / lsum;
  float2 o; o.x = a0 * inv; o.y = a1 * inv;
  *(float2*)&out[((size_t)n * TROWS + tbase + c) * 16 + g * 2] = o;
}

extern "C" void kernel_launch(void* const* d_in, const int* in_sizes, int n_in,
                              void* d_out, int out_size, void* d_ws, size_t ws_size,
                              hipStream_t stream) {
  const float* ref    = (const float*)d_in[0];
  const float* tgt    = (const float*)d_in[1];
  const float* labels = (const float*)d_in[2];
  const float* wf     = (const float*)d_in[3];
  float* out = (float*)d_out;

  unsigned short* rh = (unsigned short*)d_ws;
  unsigned short* rl = rh + (size_t)NB * RROWS * FEAT;
  unsigned short* th = rl + (size_t)NB * RROWS * FEAT;
  unsigned short* tl = th + (size_t)NB * TROWS * FEAT;

  hipLaunchKernelGGL(feat_kernel, dim3(4096), dim3(256), 0, stream,
                     ref, tgt, wf, rh, rl, th, tl);
  hipLaunchKernelGGL(flash_kernel, dim3(256), dim3(256), 0, stream,
                     rh, rl, th, tl, labels, out);
}

// Round 2
// 232.058 us; speedup vs baseline: 1.1390x; 1.1390x over previous
//
#include <hip/hip_runtime.h>
#include <stdint.h>

typedef __attribute__((ext_vector_type(8))) short short8;
typedef __attribute__((ext_vector_type(4))) float f32x4;

#define NB 8
#define RFRM 3
#define HP 32                   // H/PATCH
#define RROWS (RFRM * HP * HP)  // 3072
#define TROWS (HP * HP)         // 1024
#define FEAT 256
#define KCLS 16
#define NCHUNK 4
#define CROWS (RROWS / NCHUNK)  // 768 rows per chunk
#define CITERS (CROWS / 32)     // 24 iterations per chunk

static __device__ __forceinline__ unsigned short f2bf(float x) {
  union { float f; uint32_t u; } v; v.f = x;
  uint32_t u = v.u;
  uint32_t r = (u + 0x7fffu + ((u >> 16) & 1u)) >> 16;
  return (unsigned short)r;
}
static __device__ __forceinline__ float bf2f(unsigned short h) {
  union { uint32_t u; float f; } v; v.u = ((uint32_t)h) << 16;
  return v.f;
}

// ---------------- Stage 1: patch-embed conv (fp32 exact), emit bf16 hi/lo ----
__global__ __launch_bounds__(256) void feat_kernel(
    const float* __restrict__ ref, const float* __restrict__ tgt,
    const float* __restrict__ wf,
    unsigned short* __restrict__ rh, unsigned short* __restrict__ rl,
    unsigned short* __restrict__ th, unsigned short* __restrict__ tl) {
  __shared__ float strip[192][8];  // [k = ry*24 + kw*3+ci][patch]
  const int tid = threadIdx.x;
  const int gp0 = blockIdx.x * 8;      // first global patch id
  const int b   = gp0 >> 10;           // image 0..31
  const int pi0 = gp0 & 1023;
  const int py  = pi0 >> 5;
  const int px0 = pi0 & 31;            // multiple of 8
  const int n = b >> 2, f = b & 3;
  const float* img = (f < 3) ? (ref + (size_t)(n * 3 + f) * (256 * 256 * 3))
                             : (tgt + (size_t)n * (256 * 256 * 3));
  const float* base = img + (size_t)py * 8 * 768 + (size_t)px0 * 24;
  for (int i = tid; i < 1536; i += 256) {
    int ry = i / 192, col = i - ry * 192;
    float v = base[(size_t)ry * 768 + col];
    strip[ry * 24 + (col % 24)][col / 24] = v;
  }
  __syncthreads();
  float acc[8] = {0.f, 0.f, 0.f, 0.f, 0.f, 0.f, 0.f, 0.f};
#pragma unroll 4
  for (int k = 0; k < 192; ++k) {
    float wv = wf[k * 256 + tid];
    const float4 a  = *(const float4*)&strip[k][0];
    const float4 b4 = *(const float4*)&strip[k][4];
    acc[0] = fmaf(a.x,  wv, acc[0]);
    acc[1] = fmaf(a.y,  wv, acc[1]);
    acc[2] = fmaf(a.z,  wv, acc[2]);
    acc[3] = fmaf(a.w,  wv, acc[3]);
    acc[4] = fmaf(b4.x, wv, acc[4]);
    acc[5] = fmaf(b4.y, wv, acc[5]);
    acc[6] = fmaf(b4.z, wv, acc[6]);
    acc[7] = fmaf(b4.w, wv, acc[7]);
  }
#pragma unroll
  for (int p = 0; p < 8; ++p) {
    const int prow = py * 32 + px0 + p;
    const float v = acc[p];
    const unsigned short h  = f2bf(v);
    const unsigned short lo = f2bf(v - bf2f(h));
    if (f < 3) {
      const size_t row = (size_t)n * RROWS + (size_t)f * 1024 + prow;
      rh[row * 256 + tid] = h;
      rl[row * 256 + tid] = lo;
    } else {
      const size_t row = (size_t)n * TROWS + prow;
      th[row * 256 + tid] = h;
      tl[row * 256 + tid] = lo;
    }
  }
}

// ---------------- Stage 2a: flash partials over an R-chunk -------------------
// Grid: 8 n x 32 t-tiles x 4 chunks = 1024 blocks. 256 thr = 4 waves.
__global__ __launch_bounds__(256, 3) void flash_kernel(
    const unsigned short* __restrict__ rh, const unsigned short* __restrict__ rl,
    const unsigned short* __restrict__ th, const unsigned short* __restrict__ tl,
    const float* __restrict__ labels, float* __restrict__ part) {
  __shared__ unsigned short kh[32][264], kl[32][264];
  __shared__ float S[32][36];
  __shared__ float2 labt[32][8];

  const int tid = threadIdx.x;
  const int ch = blockIdx.x & 3;
  const int tt = (blockIdx.x >> 2) & 31;
  const int n  = blockIdx.x >> 7;
  const int tbase = tt * 32;

  const int c = tid >> 3, g = tid & 7;               // phase-B: column, k-pair
  const int w = tid >> 6, ri = w >> 1, ti = w & 1;   // MFMA tile ownership
  const int lane = tid & 63, lr = lane & 15, kc = lane >> 4;

  // Q fragments in registers (per-wave, hi/lo)
  short8 qhr[8], qlr[8];
  {
    const size_t qrow = (size_t)n * TROWS + tbase + ti * 16 + lr;
    const unsigned short* sh = th + qrow * 256 + kc * 8;
    const unsigned short* sl = tl + qrow * 256 + kc * 8;
#pragma unroll
    for (int ks = 0; ks < 8; ++ks) {
      qhr[ks] = *(const short8*)(sh + ks * 32);
      qlr[ks] = *(const short8*)(sl + ks * 32);
    }
  }

  float m = -3.0e38f, lsum = 0.f, a0 = 0.f, a1 = 0.f;

  const unsigned short* khsrc = rh + ((size_t)n * RROWS + ch * CROWS) * 256;
  const unsigned short* klsrc = rl + ((size_t)n * RROWS + ch * CROWS) * 256;
  const float* labsrc = labels + ((size_t)n * RROWS + ch * CROWS) * 16;

  for (int it = 0; it < CITERS; ++it) {
    const int rbase = it * 32;
    __syncthreads();  // prior PV reads of S/labt done before restage
    {
      const int chunk = tid & 31, r0 = tid >> 5;
#pragma unroll
      for (int s = 0; s < 4; ++s) {
        const int r = r0 + s * 8;
        *(short8*)&kh[r][chunk * 8] =
            *(const short8*)(khsrc + (size_t)(rbase + r) * 256 + chunk * 8);
        *(short8*)&kl[r][chunk * 8] =
            *(const short8*)(klsrc + (size_t)(rbase + r) * 256 + chunk * 8);
      }
      labt[tid >> 3][tid & 7] =
          *(const float2*)(labsrc + (size_t)(rbase + (tid >> 3)) * 16 + (tid & 7) * 2);
    }
    __syncthreads();
    // MFMA: S[r][t] = sum_k K[r,k]*Q[t,k], bf16x2 3-pass
    f32x4 acc = {0.f, 0.f, 0.f, 0.f};
#pragma unroll
    for (int ks = 0; ks < 8; ++ks) {
      const int ko = ks * 32 + kc * 8;
      const short8 ah = *(const short8*)&kh[ri * 16 + lr][ko];
      const short8 al = *(const short8*)&kl[ri * 16 + lr][ko];
      acc = __builtin_amdgcn_mfma_f32_16x16x32_bf16(ah, qhr[ks], acc, 0, 0, 0);
      acc = __builtin_amdgcn_mfma_f32_16x16x32_bf16(al, qhr[ks], acc, 0, 0, 0);
      acc = __builtin_amdgcn_mfma_f32_16x16x32_bf16(ah, qlr[ks], acc, 0, 0, 0);
    }
#pragma unroll
    for (int i = 0; i < 4; ++i)
      S[ri * 16 + kc * 4 + i][ti * 16 + lr] = acc[i];
    __syncthreads();
    // online softmax over the 32 new rows (8 lanes per column)
    float s0 = S[g][c], s1 = S[g + 8][c], s2 = S[g + 16][c], s3 = S[g + 24][c];
    float tmax = fmaxf(fmaxf(s0, s1), fmaxf(s2, s3));
    tmax = fmaxf(tmax, __shfl_xor(tmax, 1, 8));
    tmax = fmaxf(tmax, __shfl_xor(tmax, 2, 8));
    tmax = fmaxf(tmax, __shfl_xor(tmax, 4, 8));
    const float mnew = fmaxf(m, tmax);
    const float p0 = __expf(s0 - mnew), p1 = __expf(s1 - mnew);
    const float p2 = __expf(s2 - mnew), p3 = __expf(s3 - mnew);
    float ts = (p0 + p1) + (p2 + p3);
    ts += __shfl_xor(ts, 1, 8);
    ts += __shfl_xor(ts, 2, 8);
    ts += __shfl_xor(ts, 4, 8);
    const float fac = __expf(m - mnew);
    lsum = lsum * fac + ts;
    a0 *= fac; a1 *= fac;
    m = mnew;
    S[g][c] = p0; S[g + 8][c] = p1; S[g + 16][c] = p2; S[g + 24][c] = p3;
    // producers/consumers of column c are the same 8 lanes of one wave: no barrier
#pragma unroll 8
    for (int r = 0; r < 32; ++r) {
      const float wgt = S[r][c];
      const float2 lv = labt[r][g];
      a0 = fmaf(wgt, lv.x, a0);
      a1 = fmaf(wgt, lv.y, a1);
    }
  }
  // write partial: [pb][col][ m, l, acc0..15 ]
  float* pb = part + (size_t)(((n * 32 + tt) * NCHUNK) + ch) * (32 * 18) + c * 18;
  if (g == 0) { pb[0] = m; pb[1] = lsum; }
  pb[2 + 2 * g] = a0;
  pb[3 + 2 * g] = a1;
}

// ---------------- Stage 2b: combine chunk partials ---------------------------
// Grid: 8 n x 32 t-tiles = 256 blocks x 256 thr.
__global__ __launch_bounds__(256) void combine_kernel(
    const float* __restrict__ part, float* __restrict__ out) {
  const int tid = threadIdx.x;
  const int c = tid >> 3, g = tid & 7;
  const int tt = blockIdx.x & 31, n = blockIdx.x >> 5;
  const float* pb = part + (size_t)((n * 32 + tt) * NCHUNK) * (32 * 18) + c * 18;
  float M = -3.0e38f;
#pragma unroll
  for (int ch = 0; ch < NCHUNK; ++ch) M = fmaxf(M, pb[ch * 32 * 18]);
  float L = 0.f, o0 = 0.f, o1 = 0.f;
#pragma unroll
  for (int ch = 0; ch < NCHUNK; ++ch) {
    const float* p = pb + ch * 32 * 18;
    const float wgt = __expf(p[0] - M);
    L  = fmaf(p[1], wgt, L);
    o0 = fmaf(p[2 + 2 * g], wgt, o0);
    o1 = fmaf(p[3 + 2 * g], wgt, o1);
  }
  const float inv = 1.f / L;
  float2 o; o.x = o0 * inv; o.y = o1 * inv;
  *(float2*)&out[((size_t)n * TROWS + tt * 32 + c) * 16 + g * 2] = o;
}

extern "C" void kernel_launch(void* const* d_in, const int* in_sizes, int n_in,
                              void* d_out, int out_size, void* d_ws, size_t ws_size,
                              hipStream_t stream) {
  const float* ref    = (const float*)d_in[0];
  const float* tgt    = (const float*)d_in[1];
  const float* labels = (const float*)d_in[2];
  const float* wf     = (const float*)d_in[3];
  float* out = (float*)d_out;

  unsigned short* rh = (unsigned short*)d_ws;
  unsigned short* rl = rh + (size_t)NB * RROWS * FEAT;
  unsigned short* th = rl + (size_t)NB * RROWS * FEAT;
  unsigned short* tl = th + (size_t)NB * TROWS * FEAT;
  float* part = (float*)(tl + (size_t)NB * TROWS * FEAT);

  hipLaunchKernelGGL(feat_kernel, dim3(4096), dim3(256), 0, stream,
                     ref, tgt, wf, rh, rl, th, tl);
  hipLaunchKernelGGL(flash_kernel, dim3(8 * 32 * NCHUNK), dim3(256), 0, stream,
                     rh, rl, th, tl, labels, part);
  hipLaunchKernelGGL(combine_kernel, dim3(256), dim3(256), 0, stream,
                     part, out);
}

// Round 3
// 144.467 us; speedup vs baseline: 1.8295x; 1.6063x over previous
//
#include <hip/hip_runtime.h>
#include <stdint.h>

typedef __attribute__((ext_vector_type(8))) short short8;
typedef __attribute__((ext_vector_type(4))) float f32x4;

#define NB 8
#define RFRM 3
#define HP 32                   // H/PATCH
#define RROWS (RFRM * HP * HP)  // 3072
#define TROWS (HP * HP)         // 1024
#define FEAT 256
#define KCLS 16
#define NCHUNK 3
#define CROWS (RROWS / NCHUNK)  // 1024 rows per chunk
#define CITERS (CROWS / 32)     // 32 iterations per chunk

static __device__ __forceinline__ unsigned short f2bf(float x) {
  union { float f; uint32_t u; } v; v.f = x;
  uint32_t u = v.u;
  uint32_t r = (u + 0x7fffu + ((u >> 16) & 1u)) >> 16;
  return (unsigned short)r;
}
static __device__ __forceinline__ float bf2f(unsigned short h) {
  union { uint32_t u; float f; } v; v.u = ((uint32_t)h) << 16;
  return v.f;
}

// ---------------- Stage 1: patch-embed conv (fp32 exact), emit bf16 hi/lo ----
__global__ __launch_bounds__(256) void feat_kernel(
    const float* __restrict__ ref, const float* __restrict__ tgt,
    const float* __restrict__ wf,
    unsigned short* __restrict__ rh, unsigned short* __restrict__ rl,
    unsigned short* __restrict__ th, unsigned short* __restrict__ tl) {
  __shared__ float strip[192][8];  // [k = ry*24 + kw*3+ci][patch]
  const int tid = threadIdx.x;
  const int gp0 = blockIdx.x * 8;      // first global patch id
  const int b   = gp0 >> 10;           // image 0..31
  const int pi0 = gp0 & 1023;
  const int py  = pi0 >> 5;
  const int px0 = pi0 & 31;            // multiple of 8
  const int n = b >> 2, f = b & 3;
  const float* img = (f < 3) ? (ref + (size_t)(n * 3 + f) * (256 * 256 * 3))
                             : (tgt + (size_t)n * (256 * 256 * 3));
  const float* base = img + (size_t)py * 8 * 768 + (size_t)px0 * 24;
  for (int i = tid; i < 1536; i += 256) {
    int ry = i / 192, col = i - ry * 192;
    float v = base[(size_t)ry * 768 + col];
    strip[ry * 24 + (col % 24)][col / 24] = v;
  }
  __syncthreads();
  float acc[8] = {0.f, 0.f, 0.f, 0.f, 0.f, 0.f, 0.f, 0.f};
#pragma unroll 4
  for (int k = 0; k < 192; ++k) {
    float wv = wf[k * 256 + tid];
    const float4 a  = *(const float4*)&strip[k][0];
    const float4 b4 = *(const float4*)&strip[k][4];
    acc[0] = fmaf(a.x,  wv, acc[0]);
    acc[1] = fmaf(a.y,  wv, acc[1]);
    acc[2] = fmaf(a.z,  wv, acc[2]);
    acc[3] = fmaf(a.w,  wv, acc[3]);
    acc[4] = fmaf(b4.x, wv, acc[4]);
    acc[5] = fmaf(b4.y, wv, acc[5]);
    acc[6] = fmaf(b4.z, wv, acc[6]);
    acc[7] = fmaf(b4.w, wv, acc[7]);
  }
#pragma unroll
  for (int p = 0; p < 8; ++p) {
    const int prow = py * 32 + px0 + p;
    const float v = acc[p];
    const unsigned short h  = f2bf(v);
    const unsigned short lo = f2bf(v - bf2f(h));
    if (f < 3) {
      const size_t row = (size_t)n * RROWS + (size_t)f * 1024 + prow;
      rh[row * 256 + tid] = h;
      rl[row * 256 + tid] = lo;
    } else {
      const size_t row = (size_t)n * TROWS + prow;
      th[row * 256 + tid] = h;
      tl[row * 256 + tid] = lo;
    }
  }
}

// ---------------- Stage 2a: flash partials over an R-chunk -------------------
// Grid: 8 n x 32 t-tiles x 3 chunks = 768 blocks = exactly 3/CU resident.
__global__ __launch_bounds__(256, 3) void flash_kernel(
    const unsigned short* __restrict__ rh, const unsigned short* __restrict__ rl,
    const unsigned short* __restrict__ th, const unsigned short* __restrict__ tl,
    const float* __restrict__ labels, float* __restrict__ part) {
  __shared__ unsigned short kh[32][264], kl[32][264];  // K tile hi/lo
  __shared__ float S[32][36];                          // logits [r][t]
  __shared__ unsigned short Pb[32][40];                // P bf16 [t][r], 80B rows
  __shared__ unsigned short labT[16][40];              // labels bf16 [k][r]
  __shared__ float fac[32], Mf[32], Lf[32];

  const int tid = threadIdx.x;
  const int bid = blockIdx.x;
  const int ch = bid % 3;
  const int tt = (bid / 3) & 31;
  const int n  = bid / 96;
  const int tbase = tt * 32;

  const int c = tid >> 3, g = tid & 7;               // softmax: column t, r-pair
  const int w = tid >> 6, ri = w >> 1, ti = w & 1;   // MFMA tile ownership
  const int lane = tid & 63, lr = lane & 15, kc = lane >> 4;

  // Q fragments in registers (per-wave, hi/lo)
  short8 qhr[8], qlr[8];
  {
    const size_t qrow = (size_t)n * TROWS + tbase + ti * 16 + lr;
    const unsigned short* sh = th + qrow * 256 + kc * 8;
    const unsigned short* sl = tl + qrow * 256 + kc * 8;
#pragma unroll
    for (int ks = 0; ks < 8; ++ks) {
      qhr[ks] = *(const short8*)(sh + ks * 32);
      qlr[ks] = *(const short8*)(sl + ks * 32);
    }
  }

  float m = -3.0e38f, lsum = 0.f;
  f32x4 opv = {0.f, 0.f, 0.f, 0.f};  // PV accumulator: out[t=16*ti+4*kc+i][k=lr]

  const unsigned short* khsrc = rh + ((size_t)n * RROWS + ch * CROWS) * 256;
  const unsigned short* klsrc = rl + ((size_t)n * RROWS + ch * CROWS) * 256;
  const float* labsrc = labels + ((size_t)n * RROWS + ch * CROWS) * 16;

  for (int it = 0; it < CITERS; ++it) {
    const int rbase = it * 32;
    __syncthreads();  // b1: prior PV reads of Pb/labT/fac done
    {
      const int chunk = tid & 31, r0 = tid >> 5;
#pragma unroll
      for (int s = 0; s < 4; ++s) {
        const int r = r0 + s * 8;
        *(short8*)&kh[r][chunk * 8] =
            *(const short8*)(khsrc + (size_t)(rbase + r) * 256 + chunk * 8);
        *(short8*)&kl[r][chunk * 8] =
            *(const short8*)(klsrc + (size_t)(rbase + r) * 256 + chunk * 8);
      }
      // labels tile, transposed to [k][r], bf16
      const int r = tid >> 3, k0 = (tid & 7) * 2;
      const float2 lv = *(const float2*)(labsrc + (size_t)(rbase + r) * 16 + k0);
      labT[k0][r]     = f2bf(lv.x);
      labT[k0 + 1][r] = f2bf(lv.y);
    }
    __syncthreads();  // b2: K/labels staged
    // QK^T: S[r][t] = sum_k K[r,k]*Q[t,k], bf16x2 3-pass
    {
      f32x4 acc = {0.f, 0.f, 0.f, 0.f};
#pragma unroll
      for (int ks = 0; ks < 8; ++ks) {
        const int ko = ks * 32 + kc * 8;
        const short8 ah = *(const short8*)&kh[ri * 16 + lr][ko];
        const short8 al = *(const short8*)&kl[ri * 16 + lr][ko];
        acc = __builtin_amdgcn_mfma_f32_16x16x32_bf16(ah, qhr[ks], acc, 0, 0, 0);
        acc = __builtin_amdgcn_mfma_f32_16x16x32_bf16(al, qhr[ks], acc, 0, 0, 0);
        acc = __builtin_amdgcn_mfma_f32_16x16x32_bf16(ah, qlr[ks], acc, 0, 0, 0);
      }
#pragma unroll
      for (int i = 0; i < 4; ++i)
        S[ri * 16 + kc * 4 + i][ti * 16 + lr] = acc[i];
    }
    __syncthreads();  // b3: S complete
    // online softmax: lane (c,g) handles rows 2g,2g+1,2g+16,2g+17 of column c
    {
      const float s0 = S[2 * g][c], s1 = S[2 * g + 1][c];
      const float s2 = S[2 * g + 16][c], s3 = S[2 * g + 17][c];
      float tmax = fmaxf(fmaxf(s0, s1), fmaxf(s2, s3));
      tmax = fmaxf(tmax, __shfl_xor(tmax, 1, 8));
      tmax = fmaxf(tmax, __shfl_xor(tmax, 2, 8));
      tmax = fmaxf(tmax, __shfl_xor(tmax, 4, 8));
      const float mnew = fmaxf(m, tmax);
      const float p0 = __expf(s0 - mnew), p1 = __expf(s1 - mnew);
      const float p2 = __expf(s2 - mnew), p3 = __expf(s3 - mnew);
      float ts = (p0 + p1) + (p2 + p3);
      ts += __shfl_xor(ts, 1, 8);
      ts += __shfl_xor(ts, 2, 8);
      ts += __shfl_xor(ts, 4, 8);
      const float fc = __expf(m - mnew);
      lsum = lsum * fc + ts;
      m = mnew;
      if (g == 0) fac[c] = fc;
      *(uint32_t*)&Pb[c][2 * g]      = (uint32_t)f2bf(p0) | ((uint32_t)f2bf(p1) << 16);
      *(uint32_t*)&Pb[c][2 * g + 16] = (uint32_t)f2bf(p2) | ((uint32_t)f2bf(p3) << 16);
    }
    __syncthreads();  // b4: Pb/fac ready
    // PV via MFMA: out[t][k] += sum_r P[t][r]*labT[k][r]
    {
      const short8 pa = *(const short8*)&Pb[ti * 16 + lr][kc * 8];
      const short8 lb = *(const short8*)&labT[lr][kc * 8];
      opv[0] *= fac[ti * 16 + kc * 4 + 0];
      opv[1] *= fac[ti * 16 + kc * 4 + 1];
      opv[2] *= fac[ti * 16 + kc * 4 + 2];
      opv[3] *= fac[ti * 16 + kc * 4 + 3];
      opv = __builtin_amdgcn_mfma_f32_16x16x32_bf16(pa, lb, opv, 0, 0, 0);
    }
  }
  // epilogue: publish m/l, then ri==0 waves write partials
  if (g == 0) { Mf[c] = m; Lf[c] = lsum; }
  __syncthreads();
  if (ri == 0) {
    float* pb = part + (size_t)(((n * 32 + tt) * NCHUNK) + ch) * (32 * 18);
#pragma unroll
    for (int i = 0; i < 4; ++i) {
      const int t = ti * 16 + kc * 4 + i;
      pb[t * 18 + 2 + lr] = opv[i];
      if (lr == 0) { pb[t * 18] = Mf[t]; pb[t * 18 + 1] = Lf[t]; }
    }
  }
}

// ---------------- Stage 2b: combine chunk partials ---------------------------
// Grid: 8 n x 32 t-tiles = 256 blocks x 256 thr.
__global__ __launch_bounds__(256) void combine_kernel(
    const float* __restrict__ part, float* __restrict__ out) {
  const int tid = threadIdx.x;
  const int c = tid >> 3, g = tid & 7;
  const int tt = blockIdx.x & 31, n = blockIdx.x >> 5;
  const float* pb = part + (size_t)((n * 32 + tt) * NCHUNK) * (32 * 18) + c * 18;
  float M = -3.0e38f;
#pragma unroll
  for (int ch = 0; ch < NCHUNK; ++ch) M = fmaxf(M, pb[ch * 32 * 18]);
  float L = 0.f, o0 = 0.f, o1 = 0.f;
#pragma unroll
  for (int ch = 0; ch < NCHUNK; ++ch) {
    const float* p = pb + ch * 32 * 18;
    const float wgt = __expf(p[0] - M);
    L  = fmaf(p[1], wgt, L);
    o0 = fmaf(p[2 + 2 * g], wgt, o0);
    o1 = fmaf(p[3 + 2 * g], wgt, o1);
  }
  const float inv = 1.f / L;
  float2 o; o.x = o0 * inv; o.y = o1 * inv;
  *(float2*)&out[((size_t)n * TROWS + tt * 32 + c) * 16 + g * 2] = o;
}

extern "C" void kernel_launch(void* const* d_in, const int* in_sizes, int n_in,
                              void* d_out, int out_size, void* d_ws, size_t ws_size,
                              hipStream_t stream) {
  const float* ref    = (const float*)d_in[0];
  const float* tgt    = (const float*)d_in[1];
  const float* labels = (const float*)d_in[2];
  const float* wf     = (const float*)d_in[3];
  float* out = (float*)d_out;

  unsigned short* rh = (unsigned short*)d_ws;
  unsigned short* rl = rh + (size_t)NB * RROWS * FEAT;
  unsigned short* th = rl + (size_t)NB * RROWS * FEAT;
  unsigned short* tl = th + (size_t)NB * TROWS * FEAT;
  float* part = (float*)(tl + (size_t)NB * TROWS * FEAT);

  hipLaunchKernelGGL(feat_kernel, dim3(4096), dim3(256), 0, stream,
                     ref, tgt, wf, rh, rl, th, tl);
  hipLaunchKernelGGL(flash_kernel, dim3(8 * 32 * NCHUNK), dim3(256), 0, stream,
                     rh, rl, th, tl, labels, part);
  hipLaunchKernelGGL(combine_kernel, dim3(256), dim3(256), 0, stream,
                     part, out);
}

// Round 4
// 142.187 us; speedup vs baseline: 1.8589x; 1.0160x over previous
//
#include <hip/hip_runtime.h>
#include <stdint.h>

typedef __attribute__((ext_vector_type(8))) short short8;
typedef __attribute__((ext_vector_type(4))) float f32x4;

#define NB 8
#define RROWS 3072
#define TROWS 1024
#define FEAT 256
#define NCHUNK 6
#define CROWS 512               // 3072/6
#define CITERS 16               // 512/32
#define TT 64

#define GLOAD_LDS16(src, dst)                                                  \
  __builtin_amdgcn_global_load_lds(                                            \
      (const __attribute__((address_space(1))) void*)(src),                    \
      (__attribute__((address_space(3))) void*)(dst), 16, 0, 0)

static __device__ __forceinline__ unsigned short f2bf(float x) {
  union { float f; uint32_t u; } v; v.f = x;
  uint32_t u = v.u;
  uint32_t r = (u + 0x7fffu + ((u >> 16) & 1u)) >> 16;
  return (unsigned short)r;
}
static __device__ __forceinline__ float bf2f(unsigned short h) {
  union { uint32_t u; float f; } v; v.u = ((uint32_t)h) << 16;
  return v.f;
}

// ---------------- Stage 1: patch-embed conv (fp32 exact), emit bf16 hi/lo ----
// One block = 16 horizontally adjacent patches x 256 out channels.
__global__ __launch_bounds__(256) void feat_kernel(
    const float* __restrict__ ref, const float* __restrict__ tgt,
    const float* __restrict__ wf,
    unsigned short* __restrict__ rh, unsigned short* __restrict__ rl,
    unsigned short* __restrict__ th, unsigned short* __restrict__ tl) {
  __shared__ float strip[192][16];  // [k = ry*24 + kw*3+ci][patch]
  const int tid = threadIdx.x;
  const int gp0 = blockIdx.x * 16;     // first global patch id
  const int b   = gp0 >> 10;           // image 0..31
  const int pi0 = gp0 & 1023;
  const int py  = pi0 >> 5;
  const int px0 = pi0 & 31;            // 0 or 16
  const int n = b >> 2, f = b & 3;
  const float* img = (f < 3) ? (ref + (size_t)(n * 3 + f) * (256 * 256 * 3))
                             : (tgt + (size_t)n * (256 * 256 * 3));
  const float* base = img + (size_t)py * 8 * 768 + (size_t)px0 * 24;
  for (int i = tid; i < 3072; i += 256) {
    int ry = i / 384, col = i - ry * 384;
    strip[ry * 24 + (col % 24)][col / 24] = base[(size_t)ry * 768 + col];
  }
  __syncthreads();
  float4 ac0 = {0, 0, 0, 0}, ac1 = {0, 0, 0, 0}, ac2 = {0, 0, 0, 0}, ac3 = {0, 0, 0, 0};
#pragma unroll 2
  for (int k = 0; k < 192; ++k) {
    const float wv = wf[k * 256 + tid];
    const float4 a0 = *(const float4*)&strip[k][0];
    const float4 a1 = *(const float4*)&strip[k][4];
    const float4 a2 = *(const float4*)&strip[k][8];
    const float4 a3 = *(const float4*)&strip[k][12];
    ac0.x = fmaf(a0.x, wv, ac0.x); ac0.y = fmaf(a0.y, wv, ac0.y);
    ac0.z = fmaf(a0.z, wv, ac0.z); ac0.w = fmaf(a0.w, wv, ac0.w);
    ac1.x = fmaf(a1.x, wv, ac1.x); ac1.y = fmaf(a1.y, wv, ac1.y);
    ac1.z = fmaf(a1.z, wv, ac1.z); ac1.w = fmaf(a1.w, wv, ac1.w);
    ac2.x = fmaf(a2.x, wv, ac2.x); ac2.y = fmaf(a2.y, wv, ac2.y);
    ac2.z = fmaf(a2.z, wv, ac2.z); ac2.w = fmaf(a2.w, wv, ac2.w);
    ac3.x = fmaf(a3.x, wv, ac3.x); ac3.y = fmaf(a3.y, wv, ac3.y);
    ac3.z = fmaf(a3.z, wv, ac3.z); ac3.w = fmaf(a3.w, wv, ac3.w);
  }
  float acc[16] = {ac0.x, ac0.y, ac0.z, ac0.w, ac1.x, ac1.y, ac1.z, ac1.w,
                   ac2.x, ac2.y, ac2.z, ac2.w, ac3.x, ac3.y, ac3.z, ac3.w};
#pragma unroll
  for (int p = 0; p < 16; ++p) {
    const int prow = py * 32 + px0 + p;
    const float v = acc[p];
    const unsigned short h  = f2bf(v);
    const unsigned short lo = f2bf(v - bf2f(h));
    if (f < 3) {
      const size_t row = (size_t)n * RROWS + (size_t)f * 1024 + prow;
      rh[row * 256 + tid] = h;
      rl[row * 256 + tid] = lo;
    } else {
      const size_t row = (size_t)n * TROWS + prow;
      th[row * 256 + tid] = h;
      tl[row * 256 + tid] = lo;
    }
  }
}

// ---------------- Stage 2a: flash partials, Tt=64, K via global_load_lds -----
// Grid: 768 blocks (8 XCD-pinned n x 16 t-tiles x 6 chunks) = 3 blocks/CU.
__global__ __launch_bounds__(256, 3) void flash_kernel(
    const unsigned short* __restrict__ rh, const unsigned short* __restrict__ rl,
    const unsigned short* __restrict__ th, const unsigned short* __restrict__ tl,
    const float* __restrict__ labels, float* __restrict__ part) {
  __shared__ unsigned short kh[32 * 256];   // linear; content XOR-swizzled
  __shared__ unsigned short kl[32 * 256];
  __shared__ float S[32][66];               // logits [r][t], stride 66 (bank-clean)
  __shared__ unsigned short Pb[64][40];     // P bf16 [t][r]
  __shared__ unsigned short labT[16][40];   // labels bf16 [k][r]
  __shared__ float fac[64], Mf[64], Lf[64];

  const int tid = threadIdx.x;
  const int bid = blockIdx.x;
  const int n   = bid & 7;                  // XCD-pinned batch
  const int tmp = bid >> 3;
  const int tt  = tmp / NCHUNK;             // 0..15
  const int ch  = tmp - tt * NCHUNK;        // 0..5
  const int tbase = tt * TT;

  const int w = tid >> 6;                   // wave 0..3
  const int lane = tid & 63, lr = lane & 15, kc = lane >> 4;
  const int ri = w >> 1, th2 = w & 1;       // K-row half, t-half

  const int sc = tid >> 2, sg = tid & 3;    // softmax: col t (0..63), row-group

  // staging geometry (per thread): row-in-tile and swizzled source granule
  const int rr = tid >> 5;                  // 0..7 == row&7 for every s
  const int cg = (tid & 31) ^ rr;           // source 16B-granule (pre-swizzled)

  // Q fragments in registers: 2 t-quadrant sets, hi/lo
  short8 qh[2][8], ql[2][8];
  {
    const size_t qrow0 = (size_t)n * TROWS + tbase + 32 * th2;
#pragma unroll
    for (int tq = 0; tq < 2; ++tq) {
      const unsigned short* sh = th + (qrow0 + 16 * tq + lr) * 256 + kc * 8;
      const unsigned short* sl = tl + (qrow0 + 16 * tq + lr) * 256 + kc * 8;
#pragma unroll
      for (int ks = 0; ks < 8; ++ks) {
        qh[tq][ks] = *(const short8*)(sh + ks * 32);
        ql[tq][ks] = *(const short8*)(sl + ks * 32);
      }
    }
  }

  float m = -3.0e38f, lsum = 0.f;
  f32x4 opv = {0.f, 0.f, 0.f, 0.f};  // PV acc: out[t = 16w+4kc+i][k = lr]

  const unsigned short* khs = rh + ((size_t)n * RROWS + ch * CROWS) * 256;
  const unsigned short* kls = rl + ((size_t)n * RROWS + ch * CROWS) * 256;
  const float* labsrc = labels + ((size_t)n * RROWS + ch * CROWS) * 16;

  for (int it = 0; it < CITERS; ++it) {
    const int rbase = it * 32;
    __syncthreads();  // b1: prior QK reads of kh/kl and PV reads of Pb/labT done
    // ---- stage K tile via global_load_lds (pre-swizzled source) ----
    {
#pragma unroll
      for (int s = 0; s < 4; ++s) {
        const int row = s * 8 + rr;
        const size_t goff = (size_t)(rbase + row) * 256 + cg * 8;
        GLOAD_LDS16(khs + goff, (char*)kh + s * 4096 + w * 1024);
        GLOAD_LDS16(kls + goff, (char*)kl + s * 4096 + w * 1024);
      }
      // labels tile, transposed to [k][r], bf16
      const int r = tid >> 3, k0 = (tid & 7) * 2;
      const float2 lv = *(const float2*)(labsrc + (size_t)(rbase + r) * 16 + k0);
      labT[k0][r]     = f2bf(lv.x);
      labT[k0 + 1][r] = f2bf(lv.y);
    }
    __syncthreads();  // b2: staging complete (drains vmcnt + lgkm)
    // ---- QK^T: 2 t-quadrants per wave, bf16x2 3-pass ----
    {
      f32x4 acc0 = {0.f, 0.f, 0.f, 0.f}, acc1 = {0.f, 0.f, 0.f, 0.f};
      const int rowa = 16 * ri + lr;
      const int swz = (lr & 7) << 4;  // byte XOR within row
      const char* krow_h = (const char*)kh + rowa * 512;
      const char* krow_l = (const char*)kl + rowa * 512;
#pragma unroll
      for (int ks = 0; ks < 8; ++ks) {
        const int off = (ks * 64 + kc * 16) ^ swz;
        const short8 ah = *(const short8*)(krow_h + off);
        const short8 al = *(const short8*)(krow_l + off);
        acc0 = __builtin_amdgcn_mfma_f32_16x16x32_bf16(ah, qh[0][ks], acc0, 0, 0, 0);
        acc1 = __builtin_amdgcn_mfma_f32_16x16x32_bf16(ah, qh[1][ks], acc1, 0, 0, 0);
        acc0 = __builtin_amdgcn_mfma_f32_16x16x32_bf16(al, qh[0][ks], acc0, 0, 0, 0);
        acc1 = __builtin_amdgcn_mfma_f32_16x16x32_bf16(al, qh[1][ks], acc1, 0, 0, 0);
        acc0 = __builtin_amdgcn_mfma_f32_16x16x32_bf16(ah, ql[0][ks], acc0, 0, 0, 0);
        acc1 = __builtin_amdgcn_mfma_f32_16x16x32_bf16(ah, ql[1][ks], acc1, 0, 0, 0);
      }
#pragma unroll
      for (int i = 0; i < 4; ++i) {
        S[16 * ri + 4 * kc + i][32 * th2 + lr]      = acc0[i];
        S[16 * ri + 4 * kc + i][32 * th2 + 16 + lr] = acc1[i];
      }
    }
    __syncthreads();  // b3: S complete
    // ---- online softmax: 4 lanes per column, 8 rows each ----
    {
      float sv[8];
#pragma unroll
      for (int j = 0; j < 8; ++j) sv[j] = S[8 * sg + j][sc];
      float tmax = sv[0];
#pragma unroll
      for (int j = 1; j < 8; ++j) tmax = fmaxf(tmax, sv[j]);
      tmax = fmaxf(tmax, __shfl_xor(tmax, 1, 4));
      tmax = fmaxf(tmax, __shfl_xor(tmax, 2, 4));
      const float mnew = fmaxf(m, tmax);
      float p[8], ts = 0.f;
#pragma unroll
      for (int j = 0; j < 8; ++j) { p[j] = __expf(sv[j] - mnew); ts += p[j]; }
      ts += __shfl_xor(ts, 1, 4);
      ts += __shfl_xor(ts, 2, 4);
      const float fc = __expf(m - mnew);
      lsum = lsum * fc + ts;
      m = mnew;
      if (sg == 0) fac[sc] = fc;
#pragma unroll
      for (int u = 0; u < 4; ++u)
        *(uint32_t*)&Pb[sc][8 * sg + 2 * u] =
            (uint32_t)f2bf(p[2 * u]) | ((uint32_t)f2bf(p[2 * u + 1]) << 16);
    }
    __syncthreads();  // b4: Pb/fac ready
    // ---- PV via MFMA: wave w owns out tile t = 16w..16w+15 ----
    {
      const short8 pa = *(const short8*)&Pb[16 * w + lr][kc * 8];
      const short8 lb = *(const short8*)&labT[lr][kc * 8];
      opv[0] *= fac[16 * w + 4 * kc + 0];
      opv[1] *= fac[16 * w + 4 * kc + 1];
      opv[2] *= fac[16 * w + 4 * kc + 2];
      opv[3] *= fac[16 * w + 4 * kc + 3];
      opv = __builtin_amdgcn_mfma_f32_16x16x32_bf16(pa, lb, opv, 0, 0, 0);
    }
  }
  // epilogue
  if (sg == 0) { Mf[sc] = m; Lf[sc] = lsum; }
  __syncthreads();
  {
    float* pb = part + ((size_t)(n * 16 + tt) * NCHUNK + ch) * (TT * 18);
#pragma unroll
    for (int i = 0; i < 4; ++i) {
      const int t = 16 * w + 4 * kc + i;
      pb[t * 18 + 2 + lr] = opv[i];
      if (lr == 0) { pb[t * 18] = Mf[t]; pb[t * 18 + 1] = Lf[t]; }
    }
  }
}

// ---------------- Stage 2b: combine chunk partials ---------------------------
// Grid: 8 n x 16 t-tiles = 128 blocks x 256 thr.
__global__ __launch_bounds__(256) void combine_kernel(
    const float* __restrict__ part, float* __restrict__ out) {
  const int tid = threadIdx.x;
  const int tl = tid >> 2, g = tid & 3;   // t within tile, k-quad
  const int tt = blockIdx.x & 15, n = blockIdx.x >> 4;
  const float* pb = part + (size_t)((n * 16 + tt) * NCHUNK) * (TT * 18) + tl * 18;
  float M = -3.0e38f;
#pragma unroll
  for (int c = 0; c < NCHUNK; ++c) M = fmaxf(M, pb[c * TT * 18]);
  float L = 0.f, o0 = 0.f, o1 = 0.f, o2 = 0.f, o3 = 0.f;
#pragma unroll
  for (int c = 0; c < NCHUNK; ++c) {
    const float* p = pb + c * TT * 18;
    const float wgt = __expf(p[0] - M);
    L  = fmaf(p[1], wgt, L);
    o0 = fmaf(p[2 + 4 * g + 0], wgt, o0);
    o1 = fmaf(p[2 + 4 * g + 1], wgt, o1);
    o2 = fmaf(p[2 + 4 * g + 2], wgt, o2);
    o3 = fmaf(p[2 + 4 * g + 3], wgt, o3);
  }
  const float inv = 1.f / L;
  float4 ov; ov.x = o0 * inv; ov.y = o1 * inv; ov.z = o2 * inv; ov.w = o3 * inv;
  *(float4*)&out[((size_t)n * TROWS + tt * TT + tl) * 16 + 4 * g] = ov;
}

extern "C" void kernel_launch(void* const* d_in, const int* in_sizes, int n_in,
                              void* d_out, int out_size, void* d_ws, size_t ws_size,
                              hipStream_t stream) {
  const float* ref    = (const float*)d_in[0];
  const float* tgt    = (const float*)d_in[1];
  const float* labels = (const float*)d_in[2];
  const float* wf     = (const float*)d_in[3];
  float* out = (float*)d_out;

  unsigned short* rh = (unsigned short*)d_ws;
  unsigned short* rl = rh + (size_t)NB * RROWS * FEAT;
  unsigned short* th = rl + (size_t)NB * RROWS * FEAT;
  unsigned short* tl = th + (size_t)NB * TROWS * FEAT;
  float* part = (float*)(tl + (size_t)NB * TROWS * FEAT);

  hipLaunchKernelGGL(feat_kernel, dim3(2048), dim3(256), 0, stream,
                     ref, tgt, wf, rh, rl, th, tl);
  hipLaunchKernelGGL(flash_kernel, dim3(8 * 16 * NCHUNK), dim3(256), 0, stream,
                     rh, rl, th, tl, labels, part);
  hipLaunchKernelGGL(combine_kernel, dim3(128), dim3(256), 0, stream,
                     part, out);
}

// Round 5
// 118.355 us; speedup vs baseline: 2.2332x; 1.2014x over previous
//
#include <hip/hip_runtime.h>
#include <stdint.h>

typedef __attribute__((ext_vector_type(8))) short short8;
typedef __attribute__((ext_vector_type(4))) float f32x4;

#define NB 8
#define RROWS 3072
#define TROWS 1024
#define FEAT 256
#define NCHUNK 4
#define CROWS 768               // 3072/4
#define CITERS 24               // 768/32
#define TT 64

#define GLOAD_LDS16(src, dst)                                                  \
  __builtin_amdgcn_global_load_lds(                                            \
      (const __attribute__((address_space(1))) void*)(src),                    \
      (__attribute__((address_space(3))) void*)(dst), 16, 0, 0)

static __device__ __forceinline__ unsigned short f2bf(float x) {
  union { float f; uint32_t u; } v; v.f = x;
  uint32_t u = v.u;
  uint32_t r = (u + 0x7fffu + ((u >> 16) & 1u)) >> 16;
  return (unsigned short)r;
}
static __device__ __forceinline__ float bf2f(unsigned short h) {
  union { uint32_t u; float f; } v; v.u = ((uint32_t)h) << 16;
  return v.f;
}
static __device__ __forceinline__ uint32_t pk2(float a, float b) {
  return (uint32_t)f2bf(a) | ((uint32_t)f2bf(b) << 16);
}

// ---------------- Stage 1: patch-embed conv (fp32 exact), emit bf16 hi/lo ----
// One block = 16 horizontally adjacent patches x 256 out channels.
__global__ __launch_bounds__(256) void feat_kernel(
    const float* __restrict__ ref, const float* __restrict__ tgt,
    const float* __restrict__ wf,
    unsigned short* __restrict__ rh, unsigned short* __restrict__ rl,
    unsigned short* __restrict__ th, unsigned short* __restrict__ tl) {
  __shared__ float strip[192][16];  // [k = ry*24 + kw*3+ci][patch]
  const int tid = threadIdx.x;
  const int gp0 = blockIdx.x * 16;     // first global patch id
  const int b   = gp0 >> 10;           // image 0..31
  const int pi0 = gp0 & 1023;
  const int py  = pi0 >> 5;
  const int px0 = pi0 & 31;            // 0 or 16
  const int n = b >> 2, f = b & 3;
  const float* img = (f < 3) ? (ref + (size_t)(n * 3 + f) * (256 * 256 * 3))
                             : (tgt + (size_t)n * (256 * 256 * 3));
  const float* base = img + (size_t)py * 8 * 768 + (size_t)px0 * 24;
  for (int i = tid; i < 3072; i += 256) {
    int ry = i / 384, col = i - ry * 384;
    strip[ry * 24 + (col % 24)][col / 24] = base[(size_t)ry * 768 + col];
  }
  __syncthreads();
  float4 ac0 = {0, 0, 0, 0}, ac1 = {0, 0, 0, 0}, ac2 = {0, 0, 0, 0}, ac3 = {0, 0, 0, 0};
  float wv[4];
#pragma unroll
  for (int j = 0; j < 4; ++j) wv[j] = wf[j * 256 + tid];
  for (int k0 = 0; k0 < 192; k0 += 4) {
    float nw[4] = {0.f, 0.f, 0.f, 0.f};
    if (k0 + 4 < 192) {
#pragma unroll
      for (int j = 0; j < 4; ++j) nw[j] = wf[(k0 + 4 + j) * 256 + tid];
    }
#pragma unroll
    for (int j = 0; j < 4; ++j) {
      const float wvj = wv[j];
      const int k = k0 + j;
      const float4 a0 = *(const float4*)&strip[k][0];
      const float4 a1 = *(const float4*)&strip[k][4];
      const float4 a2 = *(const float4*)&strip[k][8];
      const float4 a3 = *(const float4*)&strip[k][12];
      ac0.x = fmaf(a0.x, wvj, ac0.x); ac0.y = fmaf(a0.y, wvj, ac0.y);
      ac0.z = fmaf(a0.z, wvj, ac0.z); ac0.w = fmaf(a0.w, wvj, ac0.w);
      ac1.x = fmaf(a1.x, wvj, ac1.x); ac1.y = fmaf(a1.y, wvj, ac1.y);
      ac1.z = fmaf(a1.z, wvj, ac1.z); ac1.w = fmaf(a1.w, wvj, ac1.w);
      ac2.x = fmaf(a2.x, wvj, ac2.x); ac2.y = fmaf(a2.y, wvj, ac2.y);
      ac2.z = fmaf(a2.z, wvj, ac2.z); ac2.w = fmaf(a2.w, wvj, ac2.w);
      ac3.x = fmaf(a3.x, wvj, ac3.x); ac3.y = fmaf(a3.y, wvj, ac3.y);
      ac3.z = fmaf(a3.z, wvj, ac3.z); ac3.w = fmaf(a3.w, wvj, ac3.w);
    }
#pragma unroll
    for (int j = 0; j < 4; ++j) wv[j] = nw[j];
  }
  float acc[16] = {ac0.x, ac0.y, ac0.z, ac0.w, ac1.x, ac1.y, ac1.z, ac1.w,
                   ac2.x, ac2.y, ac2.z, ac2.w, ac3.x, ac3.y, ac3.z, ac3.w};
#pragma unroll
  for (int p = 0; p < 16; ++p) {
    const int prow = py * 32 + px0 + p;
    const float v = acc[p];
    const unsigned short h  = f2bf(v);
    const unsigned short lo = f2bf(v - bf2f(h));
    if (f < 3) {
      const size_t row = (size_t)n * RROWS + (size_t)f * 1024 + prow;
      rh[row * 256 + tid] = h;
      rl[row * 256 + tid] = lo;
    } else {
      const size_t row = (size_t)n * TROWS + prow;
      th[row * 256 + tid] = h;
      tl[row * 256 + tid] = lo;
    }
  }
}

// ---------------- Stage 2a: flash partials, in-register softmax/PV -----------
// Grid: 512 blocks (8 XCD-pinned n x 16 t-tiles x 4 chunks) = 2 blocks/CU.
// Wave w owns t-columns 16w..16w+15 over ALL 32 K-rows of each tile.
// One __syncthreads per iteration (K double-buffer handshake).
__global__ __launch_bounds__(256, 2) void flash_kernel(
    const unsigned short* __restrict__ rh, const unsigned short* __restrict__ rl,
    const unsigned short* __restrict__ th, const unsigned short* __restrict__ tl,
    const float* __restrict__ labels, float* __restrict__ part) {
  __shared__ unsigned short kh[2][8192], kl[2][8192];  // [buf][32 rows x 256]

  const int tid = threadIdx.x;
  const int bid = blockIdx.x;
  const int n   = bid & 7;                  // XCD-pinned batch
  const int tmp = bid >> 3;
  const int tt  = tmp >> 2;                 // 0..15
  const int ch  = tmp & 3;                  // 0..3
  const int tbase = tt * TT;

  const int w = tid >> 6;                   // wave 0..3
  const int lane = tid & 63, lr = lane & 15, kc = lane >> 4;

  // staging geometry: LDS linear dest; source granule pre-swizzled by row&7
  const int rr = tid >> 5;                  // row&7 for every s-step
  const int cg = (tid & 31) ^ rr;           // source 16B-granule

  const unsigned short* khs = rh + ((size_t)n * RROWS + ch * CROWS) * 256;
  const unsigned short* kls = rl + ((size_t)n * RROWS + ch * CROWS) * 256;
  const float* labsrc = labels + ((size_t)n * RROWS + ch * CROWS) * 16;

#define STAGE(buf, itv)                                                        \
  do {                                                                         \
    const int rbase_ = (itv) * 32;                                             \
    _Pragma("unroll") for (int s = 0; s < 4; ++s) {                            \
      const int row_ = s * 8 + rr;                                             \
      const size_t goff_ = (size_t)(rbase_ + row_) * 256 + cg * 8;             \
      GLOAD_LDS16(khs + goff_, (char*)kh[buf] + s * 4096 + w * 1024);          \
      GLOAD_LDS16(kls + goff_, (char*)kl[buf] + s * 4096 + w * 1024);          \
    }                                                                          \
  } while (0)

  // Q fragments in registers: wave's 16 t-columns, hi/lo
  short8 qh[8], ql[8];
  {
    const size_t qrow = (size_t)n * TROWS + tbase + 16 * w + lr;
    const unsigned short* sh = th + qrow * 256 + kc * 8;
    const unsigned short* sl = tl + qrow * 256 + kc * 8;
#pragma unroll
    for (int ks = 0; ks < 8; ++ks) {
      qh[ks] = *(const short8*)(sh + ks * 32);
      ql[ks] = *(const short8*)(sl + ks * 32);
    }
  }

  STAGE(0, 0);
  __syncthreads();  // drains DMA (vmcnt) for buf0

  float m = -3.0e38f, lsum = 0.f;
  f32x4 opv = {0.f, 0.f, 0.f, 0.f};  // out[t = 16w+4kc+i][class = lr]
  const int swz = (lr & 7) << 4;

  for (int it = 0; it < CITERS; ++it) {
    const int rbase = it * 32;
    // labels -> registers for this tile (issued early; L2-hot, hides under QK)
    float lv[8];
#pragma unroll
    for (int j = 0; j < 8; ++j)
      lv[j] = labsrc[(size_t)(rbase + 8 * kc + j) * 16 + lr];
    // prefetch next K tile into the other buffer
    if (it + 1 < CITERS) STAGE((it + 1) & 1, it + 1);

    // ---- QK^T: full 32 rows x wave's 16 cols, bf16x2 3-pass ----
    const char* kb_h = (const char*)kh[it & 1];
    const char* kb_l = (const char*)kl[it & 1];
    const char* r0h = kb_h + lr * 512;
    const char* r1h = kb_h + (16 + lr) * 512;
    const char* r0l = kb_l + lr * 512;
    const char* r1l = kb_l + (16 + lr) * 512;
    f32x4 acc0 = {0.f, 0.f, 0.f, 0.f}, acc1 = {0.f, 0.f, 0.f, 0.f};
#pragma unroll
    for (int ks = 0; ks < 8; ++ks) {
      const int off = (ks * 64 + kc * 16) ^ swz;
      const short8 ah0 = *(const short8*)(r0h + off);
      const short8 al0 = *(const short8*)(r0l + off);
      const short8 ah1 = *(const short8*)(r1h + off);
      const short8 al1 = *(const short8*)(r1l + off);
      acc0 = __builtin_amdgcn_mfma_f32_16x16x32_bf16(ah0, qh[ks], acc0, 0, 0, 0);
      acc0 = __builtin_amdgcn_mfma_f32_16x16x32_bf16(al0, qh[ks], acc0, 0, 0, 0);
      acc0 = __builtin_amdgcn_mfma_f32_16x16x32_bf16(ah0, ql[ks], acc0, 0, 0, 0);
      acc1 = __builtin_amdgcn_mfma_f32_16x16x32_bf16(ah1, qh[ks], acc1, 0, 0, 0);
      acc1 = __builtin_amdgcn_mfma_f32_16x16x32_bf16(al1, qh[ks], acc1, 0, 0, 0);
      acc1 = __builtin_amdgcn_mfma_f32_16x16x32_bf16(ah1, ql[ks], acc1, 0, 0, 0);
    }
    // lane (lr,kc): acc0[i] = S[4kc+i][t=16w+lr], acc1[i] = S[16+4kc+i][same t]

    // ---- online softmax, fully in-register (column = lr, 4 kc-lanes) ----
    float tmax = fmaxf(fmaxf(fmaxf(acc0[0], acc0[1]), fmaxf(acc0[2], acc0[3])),
                       fmaxf(fmaxf(acc1[0], acc1[1]), fmaxf(acc1[2], acc1[3])));
    tmax = fmaxf(tmax, __shfl_xor(tmax, 16));
    tmax = fmaxf(tmax, __shfl_xor(tmax, 32));
    const float mnew = fmaxf(m, tmax);
    float e0[4], e1[4], ts = 0.f;
#pragma unroll
    for (int i = 0; i < 4; ++i) {
      e0[i] = __expf(acc0[i] - mnew);
      e1[i] = __expf(acc1[i] - mnew);
      ts += e0[i] + e1[i];
    }
    ts += __shfl_xor(ts, 16);
    ts += __shfl_xor(ts, 32);
    const float fc = __expf(m - mnew);
    lsum = lsum * fc + ts;
    m = mnew;

    // ---- pack P to bf16 + 4-lane kc-transpose -> PV A-fragment ----
    // W[kc] = [w0..w3]; target T[kc'] block-flatten (verified mapping)
    const uint32_t w0 = pk2(e0[0], e0[1]), w1 = pk2(e0[2], e0[3]);
    const uint32_t w2 = pk2(e1[0], e1[1]), w3 = pk2(e1[2], e1[3]);
    const uint32_t x0 = __shfl_xor(w0, 32), x1 = __shfl_xor(w1, 32);
    const uint32_t x2 = __shfl_xor(w2, 32), x3 = __shfl_xor(w3, 32);
    const bool h2 = (lane & 32) != 0;
    const uint32_t n0 = h2 ? x2 : w0, n1 = h2 ? x3 : w1;
    const uint32_t n2 = h2 ? w2 : x0, n3 = h2 ? w3 : x1;
    const uint32_t y0 = __shfl_xor(n0, 16), y1 = __shfl_xor(n1, 16);
    const uint32_t y2 = __shfl_xor(n2, 16), y3 = __shfl_xor(n3, 16);
    const bool h1 = (lane & 16) != 0;
    union { uint32_t u[4]; short8 s8; } pu;
    pu.u[0] = h1 ? y2 : n0;
    pu.u[1] = h1 ? y3 : n1;
    pu.u[2] = h1 ? n2 : y0;
    pu.u[3] = h1 ? n3 : y1;
    // lane (lr,kc) now holds P[t=16w+lr][r = 8kc..8kc+7] as bf16x8

    // labels B-fragment: labT[class=lr][r = 8kc..8kc+7]
    union { uint32_t u[4]; short8 s8; } lu;
    lu.u[0] = pk2(lv[0], lv[1]); lu.u[1] = pk2(lv[2], lv[3]);
    lu.u[2] = pk2(lv[4], lv[5]); lu.u[3] = pk2(lv[6], lv[7]);

    // ---- rescale + PV MFMA (in-register) ----
    const float fi0 = __shfl(fc, 4 * kc + 0, 16);
    const float fi1 = __shfl(fc, 4 * kc + 1, 16);
    const float fi2 = __shfl(fc, 4 * kc + 2, 16);
    const float fi3 = __shfl(fc, 4 * kc + 3, 16);
    opv[0] *= fi0; opv[1] *= fi1; opv[2] *= fi2; opv[3] *= fi3;
    opv = __builtin_amdgcn_mfma_f32_16x16x32_bf16(pu.s8, lu.s8, opv, 0, 0, 0);

    __syncthreads();  // drains next-tile DMA; guards buffer reuse
  }

  // epilogue: write partials (m, l, acc0..15 per column)
  float* pb = part + ((size_t)((n * 16 + tt) * NCHUNK) + ch) * (TT * 18);
#pragma unroll
  for (int i = 0; i < 4; ++i)
    pb[(16 * w + 4 * kc + i) * 18 + 2 + lr] = opv[i];
  if (kc == 0) {
    pb[(16 * w + lr) * 18] = m;
    pb[(16 * w + lr) * 18 + 1] = lsum;
  }
#undef STAGE
}

// ---------------- Stage 2b: combine chunk partials ---------------------------
// Grid: 8 n x 16 t-tiles = 128 blocks x 256 thr.
__global__ __launch_bounds__(256) void combine_kernel(
    const float* __restrict__ part, float* __restrict__ out) {
  const int tid = threadIdx.x;
  const int tw = tid >> 2, g = tid & 3;   // t within tile, k-quad
  const int tt = blockIdx.x & 15, n = blockIdx.x >> 4;
  const float* pb = part + (size_t)((n * 16 + tt) * NCHUNK) * (TT * 18) + tw * 18;
  float M = -3.0e38f;
#pragma unroll
  for (int c = 0; c < NCHUNK; ++c) M = fmaxf(M, pb[c * TT * 18]);
  float L = 0.f, o0 = 0.f, o1 = 0.f, o2 = 0.f, o3 = 0.f;
#pragma unroll
  for (int c = 0; c < NCHUNK; ++c) {
    const float* p = pb + c * TT * 18;
    const float wgt = __expf(p[0] - M);
    L  = fmaf(p[1], wgt, L);
    o0 = fmaf(p[2 + 4 * g + 0], wgt, o0);
    o1 = fmaf(p[2 + 4 * g + 1], wgt, o1);
    o2 = fmaf(p[2 + 4 * g + 2], wgt, o2);
    o3 = fmaf(p[2 + 4 * g + 3], wgt, o3);
  }
  const float inv = 1.f / L;
  float4 ov; ov.x = o0 * inv; ov.y = o1 * inv; ov.z = o2 * inv; ov.w = o3 * inv;
  *(float4*)&out[((size_t)n * TROWS + tt * TT + tw) * 16 + 4 * g] = ov;
}

extern "C" void kernel_launch(void* const* d_in, const int* in_sizes, int n_in,
                              void* d_out, int out_size, void* d_ws, size_t ws_size,
                              hipStream_t stream) {
  const float* ref    = (const float*)d_in[0];
  const float* tgt    = (const float*)d_in[1];
  const float* labels = (const float*)d_in[2];
  const float* wf     = (const float*)d_in[3];
  float* out = (float*)d_out;

  unsigned short* rh = (unsigned short*)d_ws;
  unsigned short* rl = rh + (size_t)NB * RROWS * FEAT;
  unsigned short* th = rl + (size_t)NB * RROWS * FEAT;
  unsigned short* tl = th + (size_t)NB * TROWS * FEAT;
  float* part = (float*)(tl + (size_t)NB * TROWS * FEAT);

  hipLaunchKernelGGL(feat_kernel, dim3(2048), dim3(256), 0, stream,
                     ref, tgt, wf, rh, rl, th, tl);
  hipLaunchKernelGGL(flash_kernel, dim3(8 * 16 * NCHUNK), dim3(256), 0, stream,
                     rh, rl, th, tl, labels, part);
  hipLaunchKernelGGL(combine_kernel, dim3(128), dim3(256), 0, stream,
                     part, out);
}

// Round 6
// 78.218 us; speedup vs baseline: 3.3791x; 1.5131x over previous
//
#include <hip/hip_runtime.h>
#include <stdint.h>

typedef __attribute__((ext_vector_type(8))) short short8;
typedef __attribute__((ext_vector_type(4))) float f32x4;

#define NB 8
#define RROWS 3072
#define TROWS 1024
#define FEAT 256
#define FK 192
#define NCHUNK 8
#define CROWS 384               // 3072/8
#define CITERS 12               // 384/32
#define TT 128

#define GLOAD_LDS16(src, dst)                                                  \
  __builtin_amdgcn_global_load_lds(                                            \
      (const __attribute__((address_space(1))) void*)(src),                    \
      (__attribute__((address_space(3))) void*)(dst), 16, 0, 0)

static __device__ __forceinline__ unsigned short f2bf(float x) {
  union { float f; uint32_t u; } v; v.f = x;
  uint32_t u = v.u;
  uint32_t r = (u + 0x7fffu + ((u >> 16) & 1u)) >> 16;
  return (unsigned short)r;
}
static __device__ __forceinline__ float bf2f(unsigned short h) {
  union { uint32_t u; float f; } v; v.u = ((uint32_t)h) << 16;
  return v.f;
}
static __device__ __forceinline__ uint32_t pk2(float a, float b) {
  return (uint32_t)f2bf(a) | ((uint32_t)f2bf(b) << 16);
}

// ---------------- Stage 0: transpose weights to bf16 hi/lo [o][k] ------------
__global__ void wprep_kernel(const float* __restrict__ wf,
                             unsigned short* __restrict__ wth,
                             unsigned short* __restrict__ wtl) {
  const int o = blockIdx.x, k = threadIdx.x;  // 256 blocks x 192 thr
  const float v = wf[(size_t)k * 256 + o];
  const unsigned short h = f2bf(v);
  wth[(size_t)o * FK + k] = h;
  wtl[(size_t)o * FK + k] = f2bf(v - bf2f(h));
}

// ---------------- Stage 1: patch-embed conv via MFMA (bf16x2 3-pass) ---------
// Grid: 32 images x 16 blocks (64 patches each) = 512 blocks = 2/CU.
__global__ __launch_bounds__(256, 2) void feat_kernel(
    const float* __restrict__ ref, const float* __restrict__ tgt,
    const unsigned short* __restrict__ wth, const unsigned short* __restrict__ wtl,
    unsigned short* __restrict__ rh, unsigned short* __restrict__ rl,
    unsigned short* __restrict__ th, unsigned short* __restrict__ tl) {
  __shared__ unsigned short Ah[64 * 256];  // rows 512B (24 granules used), swizzled
  __shared__ unsigned short Al[64 * 256];
  const int tid = threadIdx.x;
  const int img = blockIdx.x >> 4;   // 0..31
  const int blk = blockIdx.x & 15;   // patch-row pair (16 image rows)
  const int n = img >> 2, f = img & 3;
  const float* src = (f < 3) ? (ref + (size_t)(n * 3 + f) * (256 * 256 * 3))
                             : (tgt + (size_t)n * (256 * 256 * 3));
  const float* base = src + (size_t)blk * 16 * 768;

  // im2col staging: 3072 float4 chunks; each stays within one (p, ry) segment
#pragma unroll
  for (int j = 0; j < 12; ++j) {
    const int f4 = tid + 256 * j;
    const int y  = f4 / 192;
    const int fl = (f4 - y * 192) * 4;      // flat col in row, multiple of 4
    const float4 v = *(const float4*)(base + (size_t)y * 768 + fl);
    const int p = ((y >> 3) << 5) + fl / 24;
    const int k = (y & 7) * 24 + fl % 24;
    const int byterow = k * 2;              // multiple of 8
    const int gr  = (byterow >> 4) ^ (p & 7);
    const int off = byterow & 15;           // 0 or 8
    const unsigned short h0 = f2bf(v.x), h1 = f2bf(v.y);
    const unsigned short h2 = f2bf(v.z), h3 = f2bf(v.w);
    uint2 hw, lw;
    hw.x = (uint32_t)h0 | ((uint32_t)h1 << 16);
    hw.y = (uint32_t)h2 | ((uint32_t)h3 << 16);
    lw.x = (uint32_t)f2bf(v.x - bf2f(h0)) | ((uint32_t)f2bf(v.y - bf2f(h1)) << 16);
    lw.y = (uint32_t)f2bf(v.z - bf2f(h2)) | ((uint32_t)f2bf(v.w - bf2f(h3)) << 16);
    *(uint2*)((char*)Ah + p * 512 + gr * 16 + off) = hw;
    *(uint2*)((char*)Al + p * 512 + gr * 16 + off) = lw;
  }
  __syncthreads();

  const int w = tid >> 6, lane = tid & 63, lr = lane & 15, kc = lane >> 4;
  const size_t base_row = (f < 3) ? ((size_t)n * RROWS + (size_t)f * 1024 + blk * 64)
                                  : ((size_t)n * TROWS + blk * 64);
  unsigned short* dh = (f < 3) ? rh : th;
  unsigned short* dl = (f < 3) ? rl : tl;

#pragma unroll
  for (int ot = 0; ot < 4; ++ot) {
    const int otile = w + 4 * ot;
    // B-fragments (weights) from global, held in registers
    short8 bh[6], bl[6];
#pragma unroll
    for (int c = 0; c < 6; ++c) {
      const size_t boff = (size_t)(otile * 16 + lr) * FK + c * 32 + kc * 8;
      bh[c] = *(const short8*)(wth + boff);
      bl[c] = *(const short8*)(wtl + boff);
    }
#pragma unroll
    for (int pt = 0; pt < 4; ++pt) {
      f32x4 acc = {0.f, 0.f, 0.f, 0.f};
      const char* arow_h = (const char*)Ah + (pt * 16 + lr) * 512;
      const char* arow_l = (const char*)Al + (pt * 16 + lr) * 512;
      const int sw = (lr & 7) << 4;
#pragma unroll
      for (int c = 0; c < 6; ++c) {
        const int aoff = ((c * 4 + kc) << 4) ^ sw;
        const short8 ah = *(const short8*)(arow_h + aoff);
        const short8 al = *(const short8*)(arow_l + aoff);
        acc = __builtin_amdgcn_mfma_f32_16x16x32_bf16(ah, bh[c], acc, 0, 0, 0);
        acc = __builtin_amdgcn_mfma_f32_16x16x32_bf16(al, bh[c], acc, 0, 0, 0);
        acc = __builtin_amdgcn_mfma_f32_16x16x32_bf16(ah, bl[c], acc, 0, 0, 0);
      }
#pragma unroll
      for (int i = 0; i < 4; ++i) {
        const size_t P = base_row + pt * 16 + 4 * kc + i;
        const float v = acc[i];
        const unsigned short h = f2bf(v);
        dh[P * 256 + otile * 16 + lr] = h;
        dl[P * 256 + otile * 16 + lr] = f2bf(v - bf2f(h));
      }
    }
  }
}

// ---------------- Stage 2a: flash partials, dual Q col-sets ------------------
// Grid: 512 blocks (8 XCD-pinned n x 8 t-tiles(128) x 8 chunks) = 2/CU.
__global__ __launch_bounds__(256, 2) void flash_kernel(
    const unsigned short* __restrict__ rh, const unsigned short* __restrict__ rl,
    const unsigned short* __restrict__ th, const unsigned short* __restrict__ tl,
    const float* __restrict__ labels, float* __restrict__ part) {
  __shared__ unsigned short kh[2][8192], kl[2][8192];

  const int tid = threadIdx.x;
  const int bid = blockIdx.x;
  const int n   = bid & 7;
  const int tmp = bid >> 3;
  const int tt  = tmp >> 3;                 // 0..7
  const int ch  = tmp & 7;                  // 0..7
  const int tbase = tt * TT;

  const int w = tid >> 6;
  const int lane = tid & 63, lr = lane & 15, kc = lane >> 4;
  const int rr = tid >> 5;
  const int cg = (tid & 31) ^ rr;

  const unsigned short* khs = rh + ((size_t)n * RROWS + ch * CROWS) * 256;
  const unsigned short* kls = rl + ((size_t)n * RROWS + ch * CROWS) * 256;
  const float* labsrc = labels + ((size_t)n * RROWS + ch * CROWS) * 16;

#define STAGE(buf, itv)                                                        \
  do {                                                                         \
    const int rbase_ = (itv) * 32;                                             \
    _Pragma("unroll") for (int s = 0; s < 4; ++s) {                            \
      const int row_ = s * 8 + rr;                                             \
      const size_t goff_ = (size_t)(rbase_ + row_) * 256 + cg * 8;             \
      GLOAD_LDS16(khs + goff_, (char*)kh[buf] + s * 4096 + w * 1024);          \
      GLOAD_LDS16(kls + goff_, (char*)kl[buf] + s * 4096 + w * 1024);          \
    }                                                                          \
  } while (0)

  // Q fragments: two 16-column sets per wave, hi/lo
  short8 qh0[8], ql0[8], qh1[8], ql1[8];
  {
    const size_t qr0 = (size_t)n * TROWS + tbase + 16 * w + lr;
    const size_t qr1 = qr0 + 64;
#pragma unroll
    for (int ks = 0; ks < 8; ++ks) {
      qh0[ks] = *(const short8*)(th + qr0 * 256 + kc * 8 + ks * 32);
      ql0[ks] = *(const short8*)(tl + qr0 * 256 + kc * 8 + ks * 32);
      qh1[ks] = *(const short8*)(th + qr1 * 256 + kc * 8 + ks * 32);
      ql1[ks] = *(const short8*)(tl + qr1 * 256 + kc * 8 + ks * 32);
    }
  }

  STAGE(0, 0);
  __syncthreads();

  float m0 = -3.0e38f, l0 = 0.f, m1 = -3.0e38f, l1 = 0.f;
  f32x4 opv0 = {0.f, 0.f, 0.f, 0.f}, opv1 = {0.f, 0.f, 0.f, 0.f};
  const int swz = (lr & 7) << 4;

#define SM_PV(accA, accB, mS, lS, opvS)                                        \
  do {                                                                         \
    float tmax = fmaxf(fmaxf(fmaxf(accA[0], accA[1]), fmaxf(accA[2], accA[3])),\
                       fmaxf(fmaxf(accB[0], accB[1]), fmaxf(accB[2], accB[3])));\
    tmax = fmaxf(tmax, __shfl_xor(tmax, 16));                                  \
    tmax = fmaxf(tmax, __shfl_xor(tmax, 32));                                  \
    const float mnew = fmaxf(mS, tmax);                                        \
    float e0[4], e1[4], ts = 0.f;                                              \
    _Pragma("unroll") for (int i = 0; i < 4; ++i) {                            \
      e0[i] = __expf(accA[i] - mnew);                                          \
      e1[i] = __expf(accB[i] - mnew);                                          \
      ts += e0[i] + e1[i];                                                     \
    }                                                                          \
    ts += __shfl_xor(ts, 16);                                                  \
    ts += __shfl_xor(ts, 32);                                                  \
    const float fc = __expf(mS - mnew);                                        \
    lS = lS * fc + ts;                                                         \
    mS = mnew;                                                                 \
    const uint32_t w0 = pk2(e0[0], e0[1]), w1 = pk2(e0[2], e0[3]);             \
    const uint32_t w2 = pk2(e1[0], e1[1]), w3 = pk2(e1[2], e1[3]);             \
    const uint32_t x0 = __shfl_xor(w0, 32), x1 = __shfl_xor(w1, 32);           \
    const uint32_t x2 = __shfl_xor(w2, 32), x3 = __shfl_xor(w3, 32);           \
    const bool h2 = (lane & 32) != 0;                                          \
    const uint32_t n0 = h2 ? x2 : w0, n1 = h2 ? x3 : w1;                       \
    const uint32_t n2 = h2 ? w2 : x0, n3 = h2 ? w3 : x1;                       \
    const uint32_t y0 = __shfl_xor(n0, 16), y1 = __shfl_xor(n1, 16);           \
    const uint32_t y2 = __shfl_xor(n2, 16), y3 = __shfl_xor(n3, 16);           \
    const bool h1 = (lane & 16) != 0;                                          \
    union { uint32_t u[4]; short8 s8; } pu;                                    \
    pu.u[0] = h1 ? y2 : n0;                                                    \
    pu.u[1] = h1 ? y3 : n1;                                                    \
    pu.u[2] = h1 ? n2 : y0;                                                    \
    pu.u[3] = h1 ? n3 : y1;                                                    \
    const float fi0 = __shfl(fc, 4 * kc + 0, 16);                              \
    const float fi1 = __shfl(fc, 4 * kc + 1, 16);                              \
    const float fi2 = __shfl(fc, 4 * kc + 2, 16);                              \
    const float fi3 = __shfl(fc, 4 * kc + 3, 16);                              \
    opvS[0] *= fi0; opvS[1] *= fi1; opvS[2] *= fi2; opvS[3] *= fi3;            \
    opvS = __builtin_amdgcn_mfma_f32_16x16x32_bf16(pu.s8, lu.s8, opvS, 0, 0, 0);\
  } while (0)

  for (int it = 0; it < CITERS; ++it) {
    const int rbase = it * 32;
    float lv[8];
#pragma unroll
    for (int j = 0; j < 8; ++j)
      lv[j] = labsrc[(size_t)(rbase + 8 * kc + j) * 16 + lr];
    if (it + 1 < CITERS) STAGE((it + 1) & 1, it + 1);

    const char* kb_h = (const char*)kh[it & 1];
    const char* kb_l = (const char*)kl[it & 1];
    const char* r0h = kb_h + lr * 512;
    const char* r1h = kb_h + (16 + lr) * 512;
    const char* r0l = kb_l + lr * 512;
    const char* r1l = kb_l + (16 + lr) * 512;
    f32x4 a00 = {0.f, 0.f, 0.f, 0.f}, a01 = {0.f, 0.f, 0.f, 0.f};
    f32x4 a10 = {0.f, 0.f, 0.f, 0.f}, a11 = {0.f, 0.f, 0.f, 0.f};
#pragma unroll
    for (int ks = 0; ks < 8; ++ks) {
      const int off = (ks * 64 + kc * 16) ^ swz;
      const short8 ah0 = *(const short8*)(r0h + off);
      const short8 al0 = *(const short8*)(r0l + off);
      const short8 ah1 = *(const short8*)(r1h + off);
      const short8 al1 = *(const short8*)(r1l + off);
      a00 = __builtin_amdgcn_mfma_f32_16x16x32_bf16(ah0, qh0[ks], a00, 0, 0, 0);
      a00 = __builtin_amdgcn_mfma_f32_16x16x32_bf16(al0, qh0[ks], a00, 0, 0, 0);
      a00 = __builtin_amdgcn_mfma_f32_16x16x32_bf16(ah0, ql0[ks], a00, 0, 0, 0);
      a01 = __builtin_amdgcn_mfma_f32_16x16x32_bf16(ah1, qh0[ks], a01, 0, 0, 0);
      a01 = __builtin_amdgcn_mfma_f32_16x16x32_bf16(al1, qh0[ks], a01, 0, 0, 0);
      a01 = __builtin_amdgcn_mfma_f32_16x16x32_bf16(ah1, ql0[ks], a01, 0, 0, 0);
      a10 = __builtin_amdgcn_mfma_f32_16x16x32_bf16(ah0, qh1[ks], a10, 0, 0, 0);
      a10 = __builtin_amdgcn_mfma_f32_16x16x32_bf16(al0, qh1[ks], a10, 0, 0, 0);
      a10 = __builtin_amdgcn_mfma_f32_16x16x32_bf16(ah0, ql1[ks], a10, 0, 0, 0);
      a11 = __builtin_amdgcn_mfma_f32_16x16x32_bf16(ah1, qh1[ks], a11, 0, 0, 0);
      a11 = __builtin_amdgcn_mfma_f32_16x16x32_bf16(al1, qh1[ks], a11, 0, 0, 0);
      a11 = __builtin_amdgcn_mfma_f32_16x16x32_bf16(ah1, ql1[ks], a11, 0, 0, 0);
    }

    union { uint32_t u[4]; short8 s8; } lu;
    lu.u[0] = pk2(lv[0], lv[1]); lu.u[1] = pk2(lv[2], lv[3]);
    lu.u[2] = pk2(lv[4], lv[5]); lu.u[3] = pk2(lv[6], lv[7]);

    SM_PV(a00, a01, m0, l0, opv0);
    SM_PV(a10, a11, m1, l1, opv1);

    __syncthreads();  // drains next-tile DMA; guards buffer reuse
  }

  float* pb = part + ((size_t)(n * 8 + tt) * NCHUNK + ch) * (TT * 18);
#pragma unroll
  for (int i = 0; i < 4; ++i) {
    pb[(16 * w + 4 * kc + i) * 18 + 2 + lr] = opv0[i];
    pb[(64 + 16 * w + 4 * kc + i) * 18 + 2 + lr] = opv1[i];
  }
  if (kc == 0) {
    pb[(16 * w + lr) * 18] = m0;
    pb[(16 * w + lr) * 18 + 1] = l0;
    pb[(64 + 16 * w + lr) * 18] = m1;
    pb[(64 + 16 * w + lr) * 18 + 1] = l1;
  }
#undef STAGE
#undef SM_PV
}

// ---------------- Stage 2b: combine chunk partials ---------------------------
// Grid: 8 n x 8 t-tiles x 2 halves = 128 blocks x 256 thr.
__global__ __launch_bounds__(256) void combine_kernel(
    const float* __restrict__ part, float* __restrict__ out) {
  const int tid = threadIdx.x;
  const int tw = tid >> 2, g = tid & 3;
  const int half = blockIdx.x & 1, tt = (blockIdx.x >> 1) & 7, n = blockIdx.x >> 4;
  const float* pb = part + (size_t)((n * 8 + tt) * NCHUNK) * (TT * 18) +
                    (half * 64 + tw) * 18;
  float M = -3.0e38f;
#pragma unroll
  for (int c = 0; c < NCHUNK; ++c) M = fmaxf(M, pb[c * TT * 18]);
  float L = 0.f, o0 = 0.f, o1 = 0.f, o2 = 0.f, o3 = 0.f;
#pragma unroll
  for (int c = 0; c < NCHUNK; ++c) {
    const float* p = pb + c * TT * 18;
    const float wgt = __expf(p[0] - M);
    L  = fmaf(p[1], wgt, L);
    o0 = fmaf(p[2 + 4 * g + 0], wgt, o0);
    o1 = fmaf(p[2 + 4 * g + 1], wgt, o1);
    o2 = fmaf(p[2 + 4 * g + 2], wgt, o2);
    o3 = fmaf(p[2 + 4 * g + 3], wgt, o3);
  }
  const float inv = 1.f / L;
  float4 ov; ov.x = o0 * inv; ov.y = o1 * inv; ov.z = o2 * inv; ov.w = o3 * inv;
  *(float4*)&out[((size_t)n * TROWS + tt * TT + half * 64 + tw) * 16 + 4 * g] = ov;
}

extern "C" void kernel_launch(void* const* d_in, const int* in_sizes, int n_in,
                              void* d_out, int out_size, void* d_ws, size_t ws_size,
                              hipStream_t stream) {
  const float* ref    = (const float*)d_in[0];
  const float* tgt    = (const float*)d_in[1];
  const float* labels = (const float*)d_in[2];
  const float* wf     = (const float*)d_in[3];
  float* out = (float*)d_out;

  unsigned short* rh  = (unsigned short*)d_ws;
  unsigned short* rl  = rh + (size_t)NB * RROWS * FEAT;
  unsigned short* th  = rl + (size_t)NB * RROWS * FEAT;
  unsigned short* tl  = th + (size_t)NB * TROWS * FEAT;
  unsigned short* wth = tl + (size_t)NB * TROWS * FEAT;
  unsigned short* wtl = wth + (size_t)FEAT * FK;
  float* part = (float*)(wtl + (size_t)FEAT * FK);

  hipLaunchKernelGGL(wprep_kernel, dim3(256), dim3(192), 0, stream, wf, wth, wtl);
  hipLaunchKernelGGL(feat_kernel, dim3(512), dim3(256), 0, stream,
                     ref, tgt, wth, wtl, rh, rl, th, tl);
  hipLaunchKernelGGL(flash_kernel, dim3(8 * 8 * NCHUNK), dim3(256), 0, stream,
                     rh, rl, th, tl, labels, part);
  hipLaunchKernelGGL(combine_kernel, dim3(128), dim3(256), 0, stream,
                     part, out);
}